// Round 1
// baseline (831.544 us; speedup 1.0000x reference)
//
#include <hip/hip_runtime.h>
#include <stdint.h>

// Problem dims (fixed): x [M,K] fp32, W [K,N] fp32 ternary, b [N] fp32.
// out = concat( sign(z) [M,N], z [M,N] ), z = x@W + b, all fp32.
#define MDIM 8192
#define NDIM 4096
#define KDIM 4096

#define BM 128
#define BN 128
#define BK 64

typedef __bf16 bf16x8 __attribute__((ext_vector_type(8)));
typedef float f32x4 __attribute__((ext_vector_type(4)));

#define GPTR(p) ((const __attribute__((address_space(1))) void*)(p))
#define LPTR(p) ((__attribute__((address_space(3))) void*)(p))

__device__ __forceinline__ unsigned short f2bf(float f) {
  union { float f; uint32_t u; } c; c.f = f;
  uint32_t u = c.u;
  u += 0x7fffu + ((u >> 16) & 1u);   // RTNE (NaN irrelevant for this data)
  return (unsigned short)(u >> 16);
}

// ---------------- conversion kernels (fast path, into d_ws) ----------------

// x fp32 -> bf16, elementwise, 8 elems/thread (16B stores).
__global__ void cvt_x_kernel(const float* __restrict__ x,
                             unsigned short* __restrict__ o) {
  size_t i = ((size_t)blockIdx.x * 256 + threadIdx.x) * 8;
  const float4* p = (const float4*)(x + i);
  float4 a = p[0], b = p[1];
  uint32_t r0 = (uint32_t)f2bf(a.x) | ((uint32_t)f2bf(a.y) << 16);
  uint32_t r1 = (uint32_t)f2bf(a.z) | ((uint32_t)f2bf(a.w) << 16);
  uint32_t r2 = (uint32_t)f2bf(b.x) | ((uint32_t)f2bf(b.y) << 16);
  uint32_t r3 = (uint32_t)f2bf(b.z) | ((uint32_t)f2bf(b.w) << 16);
  *(uint4*)(o + i) = make_uint4(r0, r1, r2, r3);
}

// W [K,N] fp32 -> Wt [N,K] bf16 (transpose via LDS 64x64 tile, +1 pad).
__global__ void cvt_wt_kernel(const float* __restrict__ W,
                              unsigned short* __restrict__ Wt) {
  __shared__ float tile[64][65];
  int n0 = blockIdx.x * 64;
  int k0 = blockIdx.y * 64;
  int col = threadIdx.x & 63;
  int rb = threadIdx.x >> 6;
#pragma unroll
  for (int r = rb; r < 64; r += 4)
    tile[r][col] = W[(size_t)(k0 + r) * NDIM + n0 + col];
  __syncthreads();
#pragma unroll
  for (int r = rb; r < 64; r += 4)
    Wt[(size_t)(n0 + r) * KDIM + k0 + col] = f2bf(tile[col][r]);
}

// ---------------- shared GEMM pieces ----------------
// Wave layout: 4 waves in 2x2 (wm, wn); wave tile 64x64 = 4x4 MFMA 16x16 tiles.
// A-frag (and B^T-frag) layout for mfma_f32_16x16x32_bf16:
//   lane l holds row (l&15), k = (l>>4)*8 .. +8   (one ds_read_b128)
// C/D layout: col = lane&15, row = (lane>>4)*4 + reg   [m89/m91 verified]

__device__ __forceinline__ void mfma_step(const unsigned short* As,
                                          const unsigned short* Bs,
                                          f32x4 acc[4][4], int lane, int wm,
                                          int wn) {
#pragma unroll
  for (int kk = 0; kk < 2; ++kk) {
    bf16x8 a[4], b[4];
    const int ko = kk * 32 + (lane >> 4) * 8;
#pragma unroll
    for (int i = 0; i < 4; ++i) {
      a[i] = *(const bf16x8*)(As + (size_t)(wm * 64 + i * 16 + (lane & 15)) * BK + ko);
      b[i] = *(const bf16x8*)(Bs + (size_t)(wn * 64 + i * 16 + (lane & 15)) * BK + ko);
    }
#pragma unroll
    for (int i = 0; i < 4; ++i)
#pragma unroll
      for (int j = 0; j < 4; ++j)
        acc[i][j] =
            __builtin_amdgcn_mfma_f32_16x16x32_bf16(a[i], b[j], acc[i][j], 0, 0, 0);
  }
}

__device__ __forceinline__ void epilogue_store(const f32x4 acc[4][4],
                                               const float* __restrict__ bias,
                                               float* __restrict__ out, int m0,
                                               int n0, int lane, int wm, int wn) {
  float* zout = out + (size_t)MDIM * NDIM;  // output 1 (z) after output 0 (sign)
  const int cgrp = lane >> 4;
  const int cn = lane & 15;
#pragma unroll
  for (int j = 0; j < 4; ++j) {
    int n = n0 + wn * 64 + j * 16 + cn;
    float bv = bias[n];
#pragma unroll
    for (int i = 0; i < 4; ++i) {
      int mb = m0 + wm * 64 + i * 16 + cgrp * 4;
#pragma unroll
      for (int r = 0; r < 4; ++r) {
        float z = acc[i][j][r] + bv;
        size_t idx = (size_t)(mb + r) * NDIM + n;
        zout[idx] = z;
        out[idx] = (z >= 0.0f) ? 1.0f : -1.0f;
      }
    }
  }
}

// ---------------- fast GEMM: bf16 operands from workspace ----------------
// A = x_bf16 [M,K] row-major; Bt = Wt bf16 [N,K] row-major (B transposed).
__global__ __launch_bounds__(256) void gemm_bf16_fast(
    const unsigned short* __restrict__ Ab, const unsigned short* __restrict__ Bt,
    const float* __restrict__ bias, float* __restrict__ out) {
  __shared__ __align__(16) unsigned short As[BM * BK];
  __shared__ __align__(16) unsigned short Bs[BN * BK];

  const int tid = threadIdx.x;
  const int lane = tid & 63;
  const int wave = tid >> 6;
  const int wm = wave & 1;
  const int wn = wave >> 1;
  const int m0 = blockIdx.y * BM;
  const int n0 = blockIdx.x * BN;

  f32x4 acc[4][4];
#pragma unroll
  for (int i = 0; i < 4; ++i)
#pragma unroll
    for (int j = 0; j < 4; ++j) {
      f32x4 z = {0.0f, 0.0f, 0.0f, 0.0f};
      acc[i][j] = z;
    }

  // global_load_lds: per-lane 16B gathers -> LDS base + lane*16 (wave-uniform base).
  // Lane l covers tile row (l>>3), 16B chunk (l&7); one wave-instr = 8 rows.
  const unsigned short* Ag = Ab + (size_t)(m0 + (lane >> 3)) * KDIM + (lane & 7) * 8;
  const unsigned short* Bg = Bt + (size_t)(n0 + (lane >> 3)) * KDIM + (lane & 7) * 8;

  for (int k0 = 0; k0 < KDIM; k0 += BK) {
#pragma unroll
    for (int j = 0; j < 4; ++j) {
      const int rbase = j * 32 + wave * 8;
      __builtin_amdgcn_global_load_lds(GPTR(Ag + (size_t)rbase * KDIM + k0),
                                       LPTR(As + rbase * BK), 16, 0, 0);
      __builtin_amdgcn_global_load_lds(GPTR(Bg + (size_t)rbase * KDIM + k0),
                                       LPTR(Bs + rbase * BK), 16, 0, 0);
    }
    __syncthreads();
    mfma_step(As, Bs, acc, lane, wm, wn);
    __syncthreads();
  }

  epilogue_store(acc, bias, out, m0, n0, lane, wm, wn);
}

// ---------------- fallback GEMM: fp32 inputs, in-register bf16 conversion ----
// Used only if ws_size is too small for the staging buffers. Correctness-first.
__global__ __launch_bounds__(256) void gemm_bf16_nows(
    const float* __restrict__ x, const float* __restrict__ W,
    const float* __restrict__ bias, float* __restrict__ out) {
  __shared__ __align__(16) unsigned short As[BM * BK];
  __shared__ __align__(16) unsigned short Bs[BN * BK];

  const int tid = threadIdx.x;
  const int lane = tid & 63;
  const int wave = tid >> 6;
  const int wm = wave & 1;
  const int wn = wave >> 1;
  const int m0 = blockIdx.y * BM;
  const int n0 = blockIdx.x * BN;

  f32x4 acc[4][4];
#pragma unroll
  for (int i = 0; i < 4; ++i)
#pragma unroll
    for (int j = 0; j < 4; ++j) {
      f32x4 z = {0.0f, 0.0f, 0.0f, 0.0f};
      acc[i][j] = z;
    }

  for (int k0 = 0; k0 < KDIM; k0 += BK) {
    // A tile: 128 rows x 64 k, fp32 -> bf16.
    {
      const int chunk = (tid & 15) * 4;
      const int rowb = tid >> 4;
#pragma unroll
      for (int r = 0; r < 8; ++r) {
        int row = rowb + 16 * r;
        float4 v = *(const float4*)&x[(size_t)(m0 + row) * KDIM + k0 + chunk];
        uint2 pk;
        pk.x = (uint32_t)f2bf(v.x) | ((uint32_t)f2bf(v.y) << 16);
        pk.y = (uint32_t)f2bf(v.z) | ((uint32_t)f2bf(v.w) << 16);
        *(uint2*)&As[row * BK + chunk] = pk;
      }
    }
    // B tile: W rows k0..k0+63, cols n0..n0+127 -> Bs[n][k] (transpose scatter).
    {
      const int nc = (tid & 31) * 4;
      const int kb = tid >> 5;
#pragma unroll
      for (int r = 0; r < 8; ++r) {
        int krow = kb + 8 * r;
        float4 v = *(const float4*)&W[(size_t)(k0 + krow) * NDIM + n0 + nc];
        Bs[(nc + 0) * BK + krow] = f2bf(v.x);
        Bs[(nc + 1) * BK + krow] = f2bf(v.y);
        Bs[(nc + 2) * BK + krow] = f2bf(v.z);
        Bs[(nc + 3) * BK + krow] = f2bf(v.w);
      }
    }
    __syncthreads();
    mfma_step(As, Bs, acc, lane, wm, wn);
    __syncthreads();
  }

  epilogue_store(acc, bias, out, m0, n0, lane, wm, wn);
}

// ---------------- launcher ----------------
extern "C" void kernel_launch(void* const* d_in, const int* in_sizes, int n_in,
                              void* d_out, int out_size, void* d_ws,
                              size_t ws_size, hipStream_t stream) {
  (void)in_sizes; (void)n_in; (void)out_size;
  const float* x = (const float*)d_in[0];
  const float* W = (const float*)d_in[1];
  const float* b = (const float*)d_in[2];
  float* out = (float*)d_out;

  const size_t xb_elems = (size_t)MDIM * KDIM;
  const size_t wt_elems = (size_t)KDIM * NDIM;
  const size_t need = (xb_elems + wt_elems) * sizeof(unsigned short);

  dim3 ggrid(NDIM / BN, MDIM / BM);  // (32, 64) = 2048 blocks

  if (ws_size >= need) {
    unsigned short* xb = (unsigned short*)d_ws;
    unsigned short* wt = xb + xb_elems;
    const int nblk = (int)(xb_elems / 8 / 256);  // 16384
    cvt_x_kernel<<<nblk, 256, 0, stream>>>(x, xb);
    cvt_wt_kernel<<<dim3(NDIM / 64, KDIM / 64), 256, 0, stream>>>(W, wt);
    gemm_bf16_fast<<<ggrid, 256, 0, stream>>>(xb, wt, b, out);
  } else {
    gemm_bf16_nows<<<ggrid, 256, 0, stream>>>(x, W, b, out);
  }
}

// Round 2
// 772.812 us; speedup vs baseline: 1.0760x; 1.0760x over previous
//
#include <hip/hip_runtime.h>
#include <stdint.h>

// Problem dims (fixed): x [M,K] fp32, W [K,N] fp32 ternary, b [N] fp32.
// out = concat( sign(z) [M,N], z [M,N] ), z = x@W + b, all fp32.
#define MDIM 8192
#define NDIM 4096
#define KDIM 4096

#define BM 128
#define BN 128
#define BK 64

typedef __bf16 bf16x8 __attribute__((ext_vector_type(8)));
typedef float f32x4 __attribute__((ext_vector_type(4)));

#define GPTR(p) ((const __attribute__((address_space(1))) void*)(p))
#define LPTR(p) ((__attribute__((address_space(3))) void*)(p))

__device__ __forceinline__ unsigned short f2bf(float f) {
  union { float f; uint32_t u; } c; c.f = f;
  uint32_t u = c.u;
  u += 0x7fffu + ((u >> 16) & 1u);   // RTNE (NaN irrelevant for this data)
  return (unsigned short)(u >> 16);
}

// ---------------- conversion kernels (fast path, into d_ws) ----------------

// x fp32 -> bf16: 4 elems/thread, fully coalesced (16B loads, 8B stores).
__global__ void cvt_x_kernel(const float* __restrict__ x,
                             unsigned short* __restrict__ o) {
  size_t i = ((size_t)blockIdx.x * 256 + threadIdx.x) * 4;
  float4 a = *(const float4*)(x + i);
  uint2 r;
  r.x = (uint32_t)f2bf(a.x) | ((uint32_t)f2bf(a.y) << 16);
  r.y = (uint32_t)f2bf(a.z) | ((uint32_t)f2bf(a.w) << 16);
  *(uint2*)(o + i) = r;
}

// W [K,N] fp32 -> Wt [N,K] bf16 via 64x64 LDS tile.
// LDS T[n][k-pair] as packed uint, leading dim 37 (odd*? 37 gives n*37%32 = 5n
// -> 2-way banks on both phases). Output stores are 16B uint4.
__global__ __launch_bounds__(256) void cvt_wt_kernel(const float* __restrict__ W,
                                                     unsigned short* __restrict__ Wt) {
  __shared__ uint32_t T[64][37];
  const int t = threadIdx.x;
  const int n0 = blockIdx.x * 64;
  const int k0 = blockIdx.y * 64;
  const int nl = t & 63;
  const int kpb = t >> 6;  // 0..3
#pragma unroll
  for (int i = 0; i < 8; ++i) {
    int kp = kpb + 4 * i;  // 0..31 (pair of k rows)
    int k = 2 * kp;
    float v0 = W[(size_t)(k0 + k) * NDIM + n0 + nl];
    float v1 = W[(size_t)(k0 + k + 1) * NDIM + n0 + nl];
    T[nl][kp] = (uint32_t)f2bf(v0) | ((uint32_t)f2bf(v1) << 16);
  }
  __syncthreads();
  const int ch = t & 7;   // 16B chunk (8 k = 4 dwords)
  const int nb = t >> 3;  // 0..31
#pragma unroll
  for (int h = 0; h < 2; ++h) {
    int n = nb + 32 * h;
    uint4 v;
    v.x = T[n][ch * 4 + 0];
    v.y = T[n][ch * 4 + 1];
    v.z = T[n][ch * 4 + 2];
    v.w = T[n][ch * 4 + 3];
    *(uint4*)&Wt[(size_t)(n0 + n) * KDIM + k0 + ch * 8] = v;
  }
}

// ---------------- shared GEMM pieces ----------------
// Wave layout: 4 waves in 2x2 (wm, wn); wave tile 64x64 = 4x4 MFMA 16x16 tiles.
// LDS tiles use an XOR chunk swizzle to kill the 128B-row-stride bank aliasing:
//   element (row, chunk c) lives at byte row*128 + ((c ^ (row&7)) * 16).
// global_load_lds deposits lane l's 16B at base+l*16, so the staging lane
// fetches global chunk (l&7)^(l>>3) of row (l>>3)  -> layout above.
// Fragment reads then hit each bank quad exactly 2-way (free, m136).

__device__ __forceinline__ void mfma_step(const unsigned short* As,
                                          const unsigned short* Bs,
                                          f32x4 acc[4][4], int lane, int wm,
                                          int wn) {
  const int rA = lane & 15;
  const int key = lane & 7;  // == row&7 for all fragment rows (rows step by 16)
#pragma unroll
  for (int kk = 0; kk < 2; ++kk) {
    const int koff = ((kk * 4 + (lane >> 4)) ^ key) * 8;  // swizzled k-chunk, elems
    bf16x8 a[4], b[4];
#pragma unroll
    for (int i = 0; i < 4; ++i) {
      a[i] = *(const bf16x8*)(As + (size_t)(wm * 64 + i * 16 + rA) * BK + koff);
      b[i] = *(const bf16x8*)(Bs + (size_t)(wn * 64 + i * 16 + rA) * BK + koff);
    }
#pragma unroll
    for (int i = 0; i < 4; ++i)
#pragma unroll
      for (int j = 0; j < 4; ++j)
        acc[i][j] =
            __builtin_amdgcn_mfma_f32_16x16x32_bf16(a[i], b[j], acc[i][j], 0, 0, 0);
  }
}

__device__ __forceinline__ void epilogue_store(const f32x4 acc[4][4],
                                               const float* __restrict__ bias,
                                               float* __restrict__ out, int m0,
                                               int n0, int lane, int wm, int wn) {
  float* zout = out + (size_t)MDIM * NDIM;  // output 1 (z) after output 0 (sign)
  const int cgrp = lane >> 4;
  const int cn = lane & 15;
#pragma unroll
  for (int j = 0; j < 4; ++j) {
    int n = n0 + wn * 64 + j * 16 + cn;
    float bv = bias[n];
#pragma unroll
    for (int i = 0; i < 4; ++i) {
      int mb = m0 + wm * 64 + i * 16 + cgrp * 4;
#pragma unroll
      for (int r = 0; r < 4; ++r) {
        float z = acc[i][j][r] + bv;
        size_t idx = (size_t)(mb + r) * NDIM + n;
        zout[idx] = z;
        out[idx] = (z >= 0.0f) ? 1.0f : -1.0f;
      }
    }
  }
}

// ---------------- fast GEMM: bf16 operands from workspace ----------------
// A = x_bf16 [M,K] row-major; Bt = Wt bf16 [N,K] row-major (B transposed).
__global__ __launch_bounds__(256) void gemm_bf16_fast(
    const unsigned short* __restrict__ Ab, const unsigned short* __restrict__ Bt,
    const float* __restrict__ bias, float* __restrict__ out) {
  __shared__ __align__(16) unsigned short As[BM * BK];
  __shared__ __align__(16) unsigned short Bs[BN * BK];

  const int tid = threadIdx.x;
  const int lane = tid & 63;
  const int wave = tid >> 6;
  const int wm = wave & 1;
  const int wn = wave >> 1;
  const int m0 = blockIdx.y * BM;
  const int n0 = blockIdx.x * BN;

  f32x4 acc[4][4];
#pragma unroll
  for (int i = 0; i < 4; ++i)
#pragma unroll
    for (int j = 0; j < 4; ++j) {
      f32x4 z = {0.0f, 0.0f, 0.0f, 0.0f};
      acc[i][j] = z;
    }

  // Staging: lane l covers row (l>>3), SWIZZLED 16B chunk (l&7)^(l>>3).
  const int lr = lane >> 3;
  const int lc = (lane & 7) ^ lr;
  const unsigned short* Ag = Ab + (size_t)(m0 + lr) * KDIM + lc * 8;
  const unsigned short* Bg = Bt + (size_t)(n0 + lr) * KDIM + lc * 8;

  for (int k0 = 0; k0 < KDIM; k0 += BK) {
#pragma unroll
    for (int j = 0; j < 4; ++j) {
      const int rbase = j * 32 + wave * 8;  // multiple of 8 -> swizzle key = lr
      __builtin_amdgcn_global_load_lds(GPTR(Ag + (size_t)rbase * KDIM + k0),
                                       LPTR(As + rbase * BK), 16, 0, 0);
      __builtin_amdgcn_global_load_lds(GPTR(Bg + (size_t)rbase * KDIM + k0),
                                       LPTR(Bs + rbase * BK), 16, 0, 0);
    }
    __syncthreads();
    mfma_step(As, Bs, acc, lane, wm, wn);
    __syncthreads();
  }

  epilogue_store(acc, bias, out, m0, n0, lane, wm, wn);
}

// ---------------- fallback GEMM: fp32 inputs, in-register bf16 conversion ----
// Used only if ws_size is too small for staging buffers. Correctness-first.
__global__ __launch_bounds__(256) void gemm_bf16_nows(
    const float* __restrict__ x, const float* __restrict__ W,
    const float* __restrict__ bias, float* __restrict__ out) {
  __shared__ __align__(16) unsigned short As[BM * BK];
  __shared__ __align__(16) unsigned short Bs[BN * BK];

  const int tid = threadIdx.x;
  const int lane = tid & 63;
  const int wave = tid >> 6;
  const int wm = wave & 1;
  const int wn = wave >> 1;
  const int m0 = blockIdx.y * BM;
  const int n0 = blockIdx.x * BN;

  f32x4 acc[4][4];
#pragma unroll
  for (int i = 0; i < 4; ++i)
#pragma unroll
    for (int j = 0; j < 4; ++j) {
      f32x4 z = {0.0f, 0.0f, 0.0f, 0.0f};
      acc[i][j] = z;
    }

  for (int k0 = 0; k0 < KDIM; k0 += BK) {
    // A tile: 128 rows x 64 k, fp32 -> bf16, swizzled chunk placement.
    {
      const int kc = (tid & 15) * 4;           // k offset, 4 elems
      const int cb = kc >> 3;                  // 16B chunk index
      const int wi = kc & 7;                   // offset within chunk
      const int rowb = tid >> 4;
#pragma unroll
      for (int r = 0; r < 8; ++r) {
        int row = rowb + 16 * r;
        float4 v = *(const float4*)&x[(size_t)(m0 + row) * KDIM + k0 + kc];
        uint2 pk;
        pk.x = (uint32_t)f2bf(v.x) | ((uint32_t)f2bf(v.y) << 16);
        pk.y = (uint32_t)f2bf(v.z) | ((uint32_t)f2bf(v.w) << 16);
        *(uint2*)&As[row * BK + ((cb ^ (row & 7)) * 8) + wi] = pk;
      }
    }
    // B tile: W rows k0..k0+63, cols n0..n0+127 -> Bs[n][k] swizzled scatter.
    {
      const int nc = (tid & 31) * 4;
      const int kb = tid >> 5;
#pragma unroll
      for (int r = 0; r < 8; ++r) {
        int krow = kb + 8 * r;
        int cb = krow >> 3, wi = krow & 7;
        float4 v = *(const float4*)&W[(size_t)(k0 + krow) * NDIM + n0 + nc];
        Bs[(nc + 0) * BK + ((cb ^ ((nc + 0) & 7)) * 8) + wi] = f2bf(v.x);
        Bs[(nc + 1) * BK + ((cb ^ ((nc + 1) & 7)) * 8) + wi] = f2bf(v.y);
        Bs[(nc + 2) * BK + ((cb ^ ((nc + 2) & 7)) * 8) + wi] = f2bf(v.z);
        Bs[(nc + 3) * BK + ((cb ^ ((nc + 3) & 7)) * 8) + wi] = f2bf(v.w);
      }
    }
    __syncthreads();
    mfma_step(As, Bs, acc, lane, wm, wn);
    __syncthreads();
  }

  epilogue_store(acc, bias, out, m0, n0, lane, wm, wn);
}

// ---------------- launcher ----------------
extern "C" void kernel_launch(void* const* d_in, const int* in_sizes, int n_in,
                              void* d_out, int out_size, void* d_ws,
                              size_t ws_size, hipStream_t stream) {
  (void)in_sizes; (void)n_in; (void)out_size;
  const float* x = (const float*)d_in[0];
  const float* W = (const float*)d_in[1];
  const float* b = (const float*)d_in[2];
  float* out = (float*)d_out;

  const size_t xb_elems = (size_t)MDIM * KDIM;
  const size_t wt_elems = (size_t)KDIM * NDIM;
  const size_t need = (xb_elems + wt_elems) * sizeof(unsigned short);

  dim3 ggrid(NDIM / BN, MDIM / BM);  // (32, 64) = 2048 blocks

  if (ws_size >= need) {
    unsigned short* xb = (unsigned short*)d_ws;
    unsigned short* wt = xb + xb_elems;
    const int nblk_x = (int)(xb_elems / 4 / 256);  // 32768
    cvt_x_kernel<<<nblk_x, 256, 0, stream>>>(x, xb);
    cvt_wt_kernel<<<dim3(NDIM / 64, KDIM / 64), 256, 0, stream>>>(W, wt);
    gemm_bf16_fast<<<ggrid, 256, 0, stream>>>(xb, wt, b, out);
  } else {
    gemm_bf16_nows<<<ggrid, 256, 0, stream>>>(x, W, b, out);
  }
}

// Round 3
// 671.054 us; speedup vs baseline: 1.2392x; 1.1516x over previous
//
#include <hip/hip_runtime.h>
#include <stdint.h>

// Problem dims (fixed): x [M,K] fp32, W [K,N] fp32 ternary, b [N] fp32.
// out = concat( sign(z) [M,N], z [M,N] ), z = x@W + b, all fp32.
#define MDIM 8192
#define NDIM 4096
#define KDIM 4096

#define BM 128
#define BN 128
#define BK 64

#define CVT_X_BLOCKS 16384  // M*K/(256*8)
#define CVT_W_BLOCKS 4096   // (N/64)*(K/64)

typedef __bf16 bf16x8 __attribute__((ext_vector_type(8)));
typedef float f32x4 __attribute__((ext_vector_type(4)));

#define GPTR(p) ((const __attribute__((address_space(1))) void*)(p))
#define LPTR(p) ((__attribute__((address_space(3))) void*)(p))

__device__ __forceinline__ uint32_t f2bf(float f) {
  union { float f; uint32_t u; } c; c.f = f;
  uint32_t u = c.u;
  u += 0x7fffu + ((u >> 16) & 1u);   // RTNE (NaN irrelevant for this data)
  return u >> 16;
}

// ---------------- fused conversion kernel (one launch, concurrent) ----------
// Blocks [0, CVT_X_BLOCKS):  x fp32 -> bf16, 8 elems/thread, coalesced.
// Blocks [CVT_X_BLOCKS, +CVT_W_BLOCKS): W [K,N] -> Wt [N,K] bf16, 64x64 LDS
// transpose tile (packed-pair layout, ld=37 -> 2-way banks max, 16B out).
__global__ __launch_bounds__(256) void cvt_fused(const float* __restrict__ x,
                                                 const float* __restrict__ W,
                                                 unsigned short* __restrict__ xb,
                                                 unsigned short* __restrict__ Wt) {
  __shared__ uint32_t T[64][37];
  const int bid = blockIdx.x;
  const int t = threadIdx.x;
  if (bid < CVT_X_BLOCKS) {
    size_t i = ((size_t)bid * 256 + t) * 8;
    const float4* p = (const float4*)(x + i);
    float4 a = p[0], b = p[1];
    uint4 r;
    r.x = f2bf(a.x) | (f2bf(a.y) << 16);
    r.y = f2bf(a.z) | (f2bf(a.w) << 16);
    r.z = f2bf(b.x) | (f2bf(b.y) << 16);
    r.w = f2bf(b.z) | (f2bf(b.w) << 16);
    *(uint4*)(xb + i) = r;
  } else {
    const int wb = bid - CVT_X_BLOCKS;
    const int n0 = (wb & 63) * 64;
    const int k0 = (wb >> 6) * 64;
    const int nl = t & 63;
    const int kpb = t >> 6;  // 0..3
#pragma unroll
    for (int i = 0; i < 8; ++i) {
      int kp = kpb + 4 * i;  // pair of k rows
      int k = 2 * kp;
      float v0 = W[(size_t)(k0 + k) * NDIM + n0 + nl];
      float v1 = W[(size_t)(k0 + k + 1) * NDIM + n0 + nl];
      T[nl][kp] = f2bf(v0) | (f2bf(v1) << 16);
    }
    __syncthreads();
    const int ch = t & 7;   // 16B chunk (8 k)
    const int nb = t >> 3;  // 0..31
#pragma unroll
    for (int h = 0; h < 2; ++h) {
      int n = nb + 32 * h;
      uint4 v;
      v.x = T[n][ch * 4 + 0];
      v.y = T[n][ch * 4 + 1];
      v.z = T[n][ch * 4 + 2];
      v.w = T[n][ch * 4 + 3];
      *(uint4*)&Wt[(size_t)(n0 + n) * KDIM + k0 + ch * 8] = v;
    }
  }
}

// ---------------- shared GEMM pieces ----------------
// Wave layout: 4 waves in 2x2 (wm, wn); wave tile 64x64 = 4x4 MFMA 16x16 tiles.
// LDS XOR chunk swizzle (zero conflicts, verified R2): element (row, chunk c)
// at byte row*128 + ((c ^ (row&7)) * 16); staging lane l fetches global chunk
// (l&7)^(l>>3) of row (l>>3).
//
// OPERAND SWAP: acc[i][j] = mfma(b[j], a[i], acc) computes the m-transposed
// tile: D layout gives lane l -> m = l&15 fixed, n = (l>>4)*4 + reg, i.e.
// 4 consecutive n per lane -> float4 epilogue stores.

__device__ __forceinline__ void mfma_step(const unsigned short* As,
                                          const unsigned short* Bs,
                                          f32x4 acc[4][4], int lane, int wm,
                                          int wn) {
  const int rA = lane & 15;
  const int key = lane & 7;  // == row&7 for all fragment rows (rows step by 16)
#pragma unroll
  for (int kk = 0; kk < 2; ++kk) {
    const int koff = ((kk * 4 + (lane >> 4)) ^ key) * 8;  // swizzled k-chunk
    bf16x8 a[4], b[4];
#pragma unroll
    for (int i = 0; i < 4; ++i) {
      a[i] = *(const bf16x8*)(As + (size_t)(wm * 64 + i * 16 + rA) * BK + koff);
      b[i] = *(const bf16x8*)(Bs + (size_t)(wn * 64 + i * 16 + rA) * BK + koff);
    }
#pragma unroll
    for (int i = 0; i < 4; ++i)
#pragma unroll
      for (int j = 0; j < 4; ++j)
        acc[i][j] =
            __builtin_amdgcn_mfma_f32_16x16x32_bf16(b[j], a[i], acc[i][j], 0, 0, 0);
  }
}

__device__ __forceinline__ void epilogue_store(const f32x4 acc[4][4],
                                               const float* __restrict__ bias,
                                               float* __restrict__ out, int m0,
                                               int n0, int lane, int wm, int wn) {
  float* zout = out + (size_t)MDIM * NDIM;  // output 1 (z) after output 0 (sign)
  const int ml = lane & 15;
  const int nb4 = (lane >> 4) * 4;
#pragma unroll
  for (int i = 0; i < 4; ++i) {
    int m = m0 + wm * 64 + i * 16 + ml;
    float* zrow = zout + (size_t)m * NDIM;
    float* srow = out + (size_t)m * NDIM;
#pragma unroll
    for (int j = 0; j < 4; ++j) {
      int n = n0 + wn * 64 + j * 16 + nb4;
      float4 bv = *(const float4*)&bias[n];
      f32x4 v = acc[i][j];
      float4 z, s;
      z.x = v[0] + bv.x; z.y = v[1] + bv.y; z.z = v[2] + bv.z; z.w = v[3] + bv.w;
      s.x = (z.x >= 0.0f) ? 1.0f : -1.0f;
      s.y = (z.y >= 0.0f) ? 1.0f : -1.0f;
      s.z = (z.z >= 0.0f) ? 1.0f : -1.0f;
      s.w = (z.w >= 0.0f) ? 1.0f : -1.0f;
      *(float4*)&zrow[n] = z;
      *(float4*)&srow[n] = s;
    }
  }
}

// ---------------- fast GEMM: bf16 operands from workspace ----------------
__global__ __launch_bounds__(256, 4) void gemm_bf16_fast(
    const unsigned short* __restrict__ Ab, const unsigned short* __restrict__ Bt,
    const float* __restrict__ bias, float* __restrict__ out) {
  __shared__ __align__(16) unsigned short As[BM * BK];
  __shared__ __align__(16) unsigned short Bs[BN * BK];

  const int tid = threadIdx.x;
  const int lane = tid & 63;
  const int wave = tid >> 6;
  const int wm = wave & 1;
  const int wn = wave >> 1;
  const int m0 = blockIdx.y * BM;
  const int n0 = blockIdx.x * BN;

  f32x4 acc[4][4];
#pragma unroll
  for (int i = 0; i < 4; ++i)
#pragma unroll
    for (int j = 0; j < 4; ++j) {
      f32x4 z = {0.0f, 0.0f, 0.0f, 0.0f};
      acc[i][j] = z;
    }

  // Staging: lane l covers row (l>>3), SWIZZLED 16B chunk (l&7)^(l>>3).
  const int lr = lane >> 3;
  const int lc = (lane & 7) ^ lr;
  const unsigned short* Ag = Ab + (size_t)(m0 + lr) * KDIM + lc * 8;
  const unsigned short* Bg = Bt + (size_t)(n0 + lr) * KDIM + lc * 8;

  for (int k0 = 0; k0 < KDIM; k0 += BK) {
#pragma unroll
    for (int j = 0; j < 4; ++j) {
      const int rbase = j * 32 + wave * 8;  // multiple of 8 -> swizzle key = lr
      __builtin_amdgcn_global_load_lds(GPTR(Ag + (size_t)rbase * KDIM + k0),
                                       LPTR(As + rbase * BK), 16, 0, 0);
      __builtin_amdgcn_global_load_lds(GPTR(Bg + (size_t)rbase * KDIM + k0),
                                       LPTR(Bs + rbase * BK), 16, 0, 0);
    }
    __syncthreads();
    mfma_step(As, Bs, acc, lane, wm, wn);
    __syncthreads();
  }

  epilogue_store(acc, bias, out, m0, n0, lane, wm, wn);
}

// ---------------- fallback GEMM: fp32 inputs, in-register bf16 conversion ----
__global__ __launch_bounds__(256) void gemm_bf16_nows(
    const float* __restrict__ x, const float* __restrict__ W,
    const float* __restrict__ bias, float* __restrict__ out) {
  __shared__ __align__(16) unsigned short As[BM * BK];
  __shared__ __align__(16) unsigned short Bs[BN * BK];

  const int tid = threadIdx.x;
  const int lane = tid & 63;
  const int wave = tid >> 6;
  const int wm = wave & 1;
  const int wn = wave >> 1;
  const int m0 = blockIdx.y * BM;
  const int n0 = blockIdx.x * BN;

  f32x4 acc[4][4];
#pragma unroll
  for (int i = 0; i < 4; ++i)
#pragma unroll
    for (int j = 0; j < 4; ++j) {
      f32x4 z = {0.0f, 0.0f, 0.0f, 0.0f};
      acc[i][j] = z;
    }

  for (int k0 = 0; k0 < KDIM; k0 += BK) {
    {
      const int kc = (tid & 15) * 4;
      const int cb = kc >> 3;
      const int wi = kc & 7;
      const int rowb = tid >> 4;
#pragma unroll
      for (int r = 0; r < 8; ++r) {
        int row = rowb + 16 * r;
        float4 v = *(const float4*)&x[(size_t)(m0 + row) * KDIM + k0 + kc];
        uint2 pk;
        pk.x = f2bf(v.x) | (f2bf(v.y) << 16);
        pk.y = f2bf(v.z) | (f2bf(v.w) << 16);
        *(uint2*)&As[row * BK + ((cb ^ (row & 7)) * 8) + wi] = pk;
      }
    }
    {
      const int nc = (tid & 31) * 4;
      const int kb = tid >> 5;
#pragma unroll
      for (int r = 0; r < 8; ++r) {
        int krow = kb + 8 * r;
        int cb = krow >> 3, wi = krow & 7;
        float4 v = *(const float4*)&W[(size_t)(k0 + krow) * NDIM + n0 + nc];
        Bs[(nc + 0) * BK + ((cb ^ ((nc + 0) & 7)) * 8) + wi] = (unsigned short)f2bf(v.x);
        Bs[(nc + 1) * BK + ((cb ^ ((nc + 1) & 7)) * 8) + wi] = (unsigned short)f2bf(v.y);
        Bs[(nc + 2) * BK + ((cb ^ ((nc + 2) & 7)) * 8) + wi] = (unsigned short)f2bf(v.z);
        Bs[(nc + 3) * BK + ((cb ^ ((nc + 3) & 7)) * 8) + wi] = (unsigned short)f2bf(v.w);
      }
    }
    __syncthreads();
    mfma_step(As, Bs, acc, lane, wm, wn);
    __syncthreads();
  }

  epilogue_store(acc, bias, out, m0, n0, lane, wm, wn);
}

// ---------------- launcher ----------------
extern "C" void kernel_launch(void* const* d_in, const int* in_sizes, int n_in,
                              void* d_out, int out_size, void* d_ws,
                              size_t ws_size, hipStream_t stream) {
  (void)in_sizes; (void)n_in; (void)out_size;
  const float* x = (const float*)d_in[0];
  const float* W = (const float*)d_in[1];
  const float* b = (const float*)d_in[2];
  float* out = (float*)d_out;

  const size_t xb_elems = (size_t)MDIM * KDIM;
  const size_t wt_elems = (size_t)KDIM * NDIM;
  const size_t need = (xb_elems + wt_elems) * sizeof(unsigned short);

  dim3 ggrid(NDIM / BN, MDIM / BM);  // (32, 64) = 2048 blocks

  if (ws_size >= need) {
    unsigned short* xb = (unsigned short*)d_ws;
    unsigned short* wt = xb + xb_elems;
    cvt_fused<<<CVT_X_BLOCKS + CVT_W_BLOCKS, 256, 0, stream>>>(x, W, xb, wt);
    gemm_bf16_fast<<<ggrid, 256, 0, stream>>>(xb, wt, b, out);
  } else {
    gemm_bf16_nows<<<ggrid, 256, 0, stream>>>(x, W, b, out);
  }
}